// Round 8
// baseline (341.641 us; speedup 1.0000x reference)
//
#include <hip/hip_runtime.h>

#define NB 256   // batch
#define NS 256   // seq len == number of steps
#define NE 2     // encoder dim
#define ND 128   // decoder dim
#define NT 256   // threads per block (4 waves, 1 per SIMD)
#define NN 16    // Chebyshev nodes/degree for the h -> context map

typedef float vf4 __attribute__((ext_vector_type(4)));
typedef _Float16 f16x8 __attribute__((ext_vector_type(8)));
typedef _Float16 f16x2 __attribute__((ext_vector_type(2)));
typedef float f32x4 __attribute__((ext_vector_type(4)));

constexpr float L2E = 1.4426950408889634f;  // log2(e)
constexpr float PI_F = 3.14159265358979323846f;

// Monomial coefficients of Chebyshev T_k: T_k(h) = sum_m CT[k][m] h^m (exact ints).
__device__ const float CT[16][16] = {
 {1,0,0,0,0,0,0,0,0,0,0,0,0,0,0,0},
 {0,1,0,0,0,0,0,0,0,0,0,0,0,0,0,0},
 {-1,0,2,0,0,0,0,0,0,0,0,0,0,0,0,0},
 {0,-3,0,4,0,0,0,0,0,0,0,0,0,0,0,0},
 {1,0,-8,0,8,0,0,0,0,0,0,0,0,0,0,0},
 {0,5,0,-20,0,16,0,0,0,0,0,0,0,0,0,0},
 {-1,0,18,0,-48,0,32,0,0,0,0,0,0,0,0,0},
 {0,-7,0,56,0,-112,0,64,0,0,0,0,0,0,0,0},
 {1,0,-32,0,160,0,-256,0,128,0,0,0,0,0,0,0},
 {0,9,0,-120,0,432,0,-576,0,256,0,0,0,0,0},
 {-1,0,50,0,-400,0,1120,0,-1280,0,512,0,0,0,0,0},
 {0,-11,0,220,0,-1232,0,2816,0,-2816,0,1024,0,0,0,0},
 {1,0,-72,0,840,0,-3584,0,6912,0,-6144,0,2048,0,0,0},
 {0,13,0,-364,0,2912,0,-9984,0,16640,0,-13312,0,4096,0,0},
 {-1,0,98,0,-1568,0,9408,0,-26880,0,39424,0,-28672,0,8192,0},
 {0,-15,0,560,0,-6048,0,28800,0,-70400,0,92160,0,-61440,0,16384}};

// DPP add: x + dpp_move(x). All-VALU cross-lane (no LDS pipe, no lgkmcnt).
template <int C>
__device__ __forceinline__ float dppadd(float x) {
    return x + __builtin_bit_cast(float,
        __builtin_amdgcn_update_dpp(0, __builtin_bit_cast(int, x), C, 0xF, 0xF, true));
}
__device__ __forceinline__ float red_quad(float x) {      // sum over each quad
    x = dppadd<0xB1>(x); x = dppadd<0x4E>(x); return x;
}
__device__ __forceinline__ float red_wave64(float x) {    // valid in lane 63
    x = dppadd<0xB1>(x); x = dppadd<0x4E>(x); x = dppadd<0x141>(x);
    x = dppadd<0x140>(x); x = dppadd<0x142>(x); x = dppadd<0x143>(x); return x;
}
// All-lane 16-sum via mirror stages (each is a permutation => valid everywhere).
__device__ __forceinline__ float red16_all(float x) {
    x = dppadd<0xB1>(x);   // xor1 (quad perm)
    x = dppadd<0x4E>(x);   // xor2 (quad perm)
    x = dppadd<0x141>(x);  // row half mirror
    x = dppadd<0x140>(x);  // row mirror
    return x;
}

// One block per batch element; 256-step recurrence in-block, ONE barrier/step.
// NT=256 (4 waves, 1/SIMD). Gate matvec split across BOTH pipes:
//   gates f,g (the c-critical pair) -> MFMA, 16 instr/wave/step
//   gates i,o (sigmoid, slope<=1/4) -> v_dot2_f32_f16, FULL K=128 per lane
//     (64 fdot2/gate; both redundancy copies compute identically -- no
//      cross-lane combine, no permlane, no bpermute; h read as 16 fully
//      lane-uniform broadcast ds_read_b128, free in the bank model).
// This halves the matrix-pipe serial segment (round-6 counters: ~490cy of a
// ~2040cy step) while the added fdot2 issue (~256cy) rides the ~74% idle
// VALU, interleaved into the MFMA gaps.
// x(k) stays writer-side (round-3 proven): parity-split poly at own f32 h +
// red_wave64 + xwbuf; head does one broadcast LDS read + red_quad.
__global__ __launch_bounds__(NT, 1)
void attn_lstm_decoder(const float* __restrict__ enc,   // [B,S,E]
                       const float* __restrict__ W1w,   // [S,S]
                       const float* __restrict__ W1b,   // [S]
                       const float* __restrict__ W2w,   // [S,2S]
                       const float* __restrict__ W2b,   // [S]
                       const float* __restrict__ Wih,   // [4D,E]
                       const float* __restrict__ Whh,   // [4D,D]
                       const float* __restrict__ bih,   // [4D]
                       const float* __restrict__ bhh,   // [4D]
                       float* __restrict__ out)         // [S,B,D]
{
    const int b    = blockIdx.x;
    const int t    = threadIdx.x;
    const int wave = t >> 6;          // 0..3
    const int lane = t & 63;
    const int grp  = lane >> 4;       // 0..3: MFMA k-group
    const int nib  = lane & 15;       // MFMA n-index
    const int sub  = grp & 1;         // which 16-block of the wave's 32 ch
    const int cpy  = grp >> 1;        // redundancy copy / poly parity
    const int gl   = 32 * wave + 16 * sub + nib;   // this thread's channel

    __shared__ __align__(16) _Float16 hist16[2 * ND];   // f16 h double buffer
    __shared__ __align__(16) float xwbuf[2][8];         // 4 waves x float2
    __shared__ float A2_l[NS];
    __shared__ float g2_l[NS];
    __shared__ float e0_l[NS];
    __shared__ float e1_l[NS];
    __shared__ float Ml[NN * NN];
    __shared__ float2 Pn[NN];
    __shared__ float2 Vl[NN];
    __shared__ float Pm0[NN], Pm1[NN];

    // ---------------- setup (once per block) ----------------
    #pragma unroll
    for (int i = t; i < NS * NE; i += NT) {
        float v = enc[b * (NS * NE) + i];      // coalesced
        if (i & 1) e1_l[i >> 1] = v; else e0_l[i >> 1] = v;
    }
    {   // t covers exactly NN*NN = 256
        const int mi = t >> 4, mj = t & 15;
        const float w = (mi == 0) ? (1.0f / NN) : (2.0f / NN);
        Ml[t] = w * __cosf((float)(mi * (2 * mj + 1)) * (PI_F / (2 * NN)));
    }
    __syncthreads();

    // w1sum rows and w2term rows: 64 rows per wave (DPP reductions).
    for (int r = 0; r < 64; ++r) {
        const int s = wave * 64 + r;
        float p = W1w[s * NS + lane]       + W1w[s * NS + lane + 64]
                + W1w[s * NS + lane + 128] + W1w[s * NS + lane + 192];
        p = red_wave64(p);
        if (lane == 63) g2_l[s] = p * (2.0f * L2E);
        float qq = 0.0f;
        #pragma unroll
        for (int kk = 0; kk < 8; ++kk) {
            const int c = lane + kk * 64;
            const float ev = (c & 1) ? e1_l[c >> 1] : e0_l[c >> 1];
            qq = fmaf(ev, W2w[s * (2 * NS) + c], qq);
        }
        qq = red_wave64(qq);
        if (lane == 63) A2_l[s] = (qq + W2b[s] + W1b[s]) * (2.0f * L2E);
    }
    __syncthreads();

    // One-time node softmax: F(y_j), one node per 16-lane group (16 total).
    {
        const int jn = 4 * wave + grp;
        const float y  = __cosf((float)(2 * jn + 1) * (PI_F / (2 * NN)));
        const float C2 = -2.0f * L2E;
        float l = 0.0f, p0 = 0.0f, p1 = 0.0f;
        #pragma unroll
        for (int k = 0; k < 16; ++k) {
            const int s = k * 16 + nib;
            const float m1 = fmaf(y, g2_l[s], A2_l[s]);
            const float u  = __builtin_amdgcn_exp2f(m1);
            const float rc = __builtin_amdgcn_rcpf(u + 1.0f);
            const float e  = __builtin_amdgcn_exp2f(rc * C2);
            l += e;
            p0 = fmaf(e, e0_l[s], p0);
            p1 = fmaf(e, e1_l[s], p1);
        }
        l = red16_all(l); p0 = red16_all(p0); p1 = red16_all(p1);
        if (nib == 0) {
            const float rl = __builtin_amdgcn_rcpf(l);
            Pn[jn] = make_float2(p0 * rl, p1 * rl);
        }
    }
    __syncthreads();

    // DCT collapse: V[i] = sum_j M[i][j]*Pn[j], 1/ND folded in.
    if (t < NN) {
        float v0 = 0.0f, v1 = 0.0f;
        #pragma unroll
        for (int j = 0; j < NN; ++j) {
            v0 = fmaf(Ml[t * NN + j], Pn[j].x, v0);
            v1 = fmaf(Ml[t * NN + j], Pn[j].y, v1);
        }
        Vl[t] = make_float2(v0 * (1.0f / ND), v1 * (1.0f / ND));
    }

    // MFMA B-fragments for gates f (rows 128..256) and g (rows 256..384):
    // tile (jj,s) covers rows 128*(jj+1) + 32*wave + 16*s + [0,16).
    // Lane holds B[k][n]: n = nib, k = 32*kt + 8*grp + e (contiguous 8).
    f16x8 wf[2][2][4];
    #pragma unroll
    for (int jj = 0; jj < 2; ++jj) {
        #pragma unroll
        for (int s = 0; s < 2; ++s) {
            const int row = 128 * (jj + 1) + 32 * wave + 16 * s + nib;
            #pragma unroll
            for (int kt = 0; kt < 4; ++kt) {
                const vf4 wa = *reinterpret_cast<const vf4*>(Whh + row * ND + 32 * kt + 8 * grp);
                const vf4 wb = *reinterpret_cast<const vf4*>(Whh + row * ND + 32 * kt + 8 * grp + 4);
                f16x8 wv;
                wv[0] = (_Float16)wa.x; wv[1] = (_Float16)wa.y;
                wv[2] = (_Float16)wa.z; wv[3] = (_Float16)wa.w;
                wv[4] = (_Float16)wb.x; wv[5] = (_Float16)wb.y;
                wv[6] = (_Float16)wb.z; wv[7] = (_Float16)wb.w;
                wf[jj][s][kt] = wv;
            }
        }
    }
    // fdot2 weights, FULL K=128, for gates i (rows 0+gl) and o (rows 384+gl).
    // wti[j]/wto[j] cover h elements 2j, 2j+1.
    f16x2 wti[64], wto[64];
    {
        const float* ri = Whh + (0   + gl) * ND;
        const float* ro = Whh + (384 + gl) * ND;
        #pragma unroll
        for (int i2 = 0; i2 < 32; ++i2) {
            const vf4 a = reinterpret_cast<const vf4*>(ri)[i2];
            wti[2 * i2]     = f16x2{(_Float16)a.x, (_Float16)a.y};
            wti[2 * i2 + 1] = f16x2{(_Float16)a.z, (_Float16)a.w};
            const vf4 c = reinterpret_cast<const vf4*>(ro)[i2];
            wto[2 * i2]     = f16x2{(_Float16)c.x, (_Float16)c.y};
            wto[2 * i2 + 1] = f16x2{(_Float16)c.z, (_Float16)c.w};
        }
    }
    // All-4-gate per-lane constants for this thread's channel gl.
    float wi0_[4], wi1_[4], bb_[4];
    #pragma unroll
    for (int j = 0; j < 4; ++j) {
        const int r = 128 * j + gl;
        wi0_[j] = Wih[r * 2 + 0];
        wi1_[j] = Wih[r * 2 + 1];
        bb_[j]  = bih[r] + bhh[r];
    }

    // zero-init both h buffers
    if (t < 2 * ND) hist16[t] = (_Float16)0.0f;
    float h_reg = 0.0f, c_reg = 0.0f;
    __syncthreads();                   // Vl visible

    // Chebyshev -> monomial: Pm[m] = sum_k V[k] * CT[k][m].
    if (t < NN) {
        float s0 = 0.0f, s1 = 0.0f;
        #pragma unroll
        for (int k = 0; k < NN; ++k) {
            s0 = fmaf(Vl[k].x, CT[k][t], s0);
            s1 = fmaf(Vl[k].y, CT[k][t], s1);
        }
        Pm0[t] = s0; Pm1[t] = s1;
    }
    __syncthreads();                   // Pm visible

    // cpy-split coefficients: cpy=0 -> even monomials, cpy=1 -> odd.
    float cc0[8], cc1[8];
    #pragma unroll
    for (int i = 0; i < 8; ++i) {
        cc0[i] = Pm0[2 * i + cpy];
        cc1[i] = Pm1[2 * i + cpy];
    }

    // phaseG: this thread's half (parity cpy) of G(h) at its own f32 h;
    // wave sum over 64 lanes (32 ch x 2 parities) = the wave's x partial.
    auto phaseG = [&](float h, int pw) {
        const float h2 = h * h;
        float v0 = cc0[7], v1 = cc1[7];
        #pragma unroll
        for (int k = 6; k >= 0; --k) {
            v0 = fmaf(v0, h2, cc0[k]);
            v1 = fmaf(v1, h2, cc1[k]);
        }
        const float hsel = cpy ? h : 1.0f;
        v0 *= hsel;
        v1 *= hsel;
        v0 = red_wave64(v0); v1 = red_wave64(v1);
        if (lane == 63) {
            xwbuf[pw][2 * wave + 0] = v0;
            xwbuf[pw][2 * wave + 1] = v1;
        }
    };

    phaseG(0.0f, 0);       // x for step 0 (h = 0)
    __syncthreads();

    // ---------------- the recurrence (ONE barrier per step) ----------------
    for (int step = 0; step < NS; ++step) {
        const int pr = step & 1;
        const int rs = pr ^ 1;            // buffer holding h(step-1)
        const int ws = pr;                // buffer for h(step)
        const _Float16* hb = &hist16[rs * ND];

        // x partial read + MFMA A fragments (each 16-lane group reads the
        // SAME 16B of h => broadcast; all C rows identical).
        float2 xv = *reinterpret_cast<const float2*>(&xwbuf[pr][2 * (lane & 3)]);
        f16x8 afr[4];
        #pragma unroll
        for (int kt = 0; kt < 4; ++kt)
            afr[kt] = __builtin_bit_cast(f16x8,
                *reinterpret_cast<const int4*>(hb + 32 * kt + 8 * grp));

        // Dual-pipe gate compute, interleaved per k-quarter:
        //   {4 b128 uniform h reads; 4 MFMA (f,g); 32 fdot2 (i,o)}.
        f32x4 mf0 = {0,0,0,0}, mf1 = {0,0,0,0};
        f32x4 mg0 = {0,0,0,0}, mg1 = {0,0,0,0};
        float ia[4] = {0.f, 0.f, 0.f, 0.f};
        float oa[4] = {0.f, 0.f, 0.f, 0.f};
        #pragma unroll
        for (int kt = 0; kt < 4; ++kt) {
            // h quarter [32*kt, 32*kt+32): fully lane-uniform broadcast reads.
            const int4 h0 = *reinterpret_cast<const int4*>(hb + 32 * kt);
            const int4 h1 = *reinterpret_cast<const int4*>(hb + 32 * kt + 8);
            const int4 h2 = *reinterpret_cast<const int4*>(hb + 32 * kt + 16);
            const int4 h3 = *reinterpret_cast<const int4*>(hb + 32 * kt + 24);
            f16x2 hq[16];
            hq[0]  = __builtin_bit_cast(f16x2, h0.x); hq[1]  = __builtin_bit_cast(f16x2, h0.y);
            hq[2]  = __builtin_bit_cast(f16x2, h0.z); hq[3]  = __builtin_bit_cast(f16x2, h0.w);
            hq[4]  = __builtin_bit_cast(f16x2, h1.x); hq[5]  = __builtin_bit_cast(f16x2, h1.y);
            hq[6]  = __builtin_bit_cast(f16x2, h1.z); hq[7]  = __builtin_bit_cast(f16x2, h1.w);
            hq[8]  = __builtin_bit_cast(f16x2, h2.x); hq[9]  = __builtin_bit_cast(f16x2, h2.y);
            hq[10] = __builtin_bit_cast(f16x2, h2.z); hq[11] = __builtin_bit_cast(f16x2, h2.w);
            hq[12] = __builtin_bit_cast(f16x2, h3.x); hq[13] = __builtin_bit_cast(f16x2, h3.y);
            hq[14] = __builtin_bit_cast(f16x2, h3.z); hq[15] = __builtin_bit_cast(f16x2, h3.w);

            mf0 = __builtin_amdgcn_mfma_f32_16x16x32_f16(afr[kt], wf[0][0][kt], mf0, 0, 0, 0);
            mf1 = __builtin_amdgcn_mfma_f32_16x16x32_f16(afr[kt], wf[0][1][kt], mf1, 0, 0, 0);
            mg0 = __builtin_amdgcn_mfma_f32_16x16x32_f16(afr[kt], wf[1][0][kt], mg0, 0, 0, 0);
            mg1 = __builtin_amdgcn_mfma_f32_16x16x32_f16(afr[kt], wf[1][1][kt], mg1, 0, 0, 0);

            #pragma unroll
            for (int p = 0; p < 16; ++p) {
                ia[p & 3] = __builtin_amdgcn_fdot2(wti[16 * kt + p], hq[p], ia[p & 3], false);
                oa[p & 3] = __builtin_amdgcn_fdot2(wto[16 * kt + p], hq[p], oa[p & 3], false);
            }
        }

        // x from the 4 wave partials (broadcast read + quad reduce).
        const float x0 = red_quad(xv.x);
        const float x1 = red_quad(xv.y);
        float bt[4];
        #pragma unroll
        for (int j = 0; j < 4; ++j)
            bt[j] = fmaf(x0, wi0_[j], fmaf(x1, wi1_[j], bb_[j]));

        const float di = (ia[0] + ia[1]) + (ia[2] + ia[3]);
        const float dz = (oa[0] + oa[1]) + (oa[2] + oa[3]);

        const float gi = di + bt[0];
        const float gf = (sub ? mf1[0] : mf0[0]) + bt[1];
        const float gg = (sub ? mg1[0] : mg0[0]) + bt[2];
        const float go = dz + bt[3];

        const float si = __builtin_amdgcn_rcpf(1.0f + __builtin_amdgcn_exp2f(-L2E * gi));
        const float sf = __builtin_amdgcn_rcpf(1.0f + __builtin_amdgcn_exp2f(-L2E * gf));
        const float so = __builtin_amdgcn_rcpf(1.0f + __builtin_amdgcn_exp2f(-L2E * go));
        const float tg = 1.0f - 2.0f * __builtin_amdgcn_rcpf(
            __builtin_amdgcn_exp2f(2.0f * L2E * gg) + 1.0f);
        c_reg = fmaf(sf, c_reg, si * tg);
        const float tc2 = 1.0f - 2.0f * __builtin_amdgcn_rcpf(
            __builtin_amdgcn_exp2f(2.0f * L2E * c_reg) + 1.0f);
        h_reg = so * tc2;

        // Tail: one f16 LDS write per channel (+ fire-and-forget global).
        if (cpy == 0) {
            hist16[ws * ND + gl] = (_Float16)h_reg;
            out[(size_t)step * (NB * ND) + b * ND + gl] = h_reg;  // async
        }
        phaseG(h_reg, pr ^ 1);                            // x for step k+1

        // LDS-only drain + raw barrier: global stores stay in flight.
        asm volatile("s_waitcnt lgkmcnt(0)" ::: "memory");
        __builtin_amdgcn_s_barrier();
    }
}

extern "C" void kernel_launch(void* const* d_in, const int* in_sizes, int n_in,
                              void* d_out, int out_size, void* d_ws, size_t ws_size,
                              hipStream_t stream) {
    const float* enc = (const float*)d_in[0];
    const float* W1w = (const float*)d_in[1];
    const float* W1b = (const float*)d_in[2];
    const float* W2w = (const float*)d_in[3];
    const float* W2b = (const float*)d_in[4];
    const float* Wih = (const float*)d_in[5];
    const float* Whh = (const float*)d_in[6];
    const float* bih = (const float*)d_in[7];
    const float* bhh = (const float*)d_in[8];
    attn_lstm_decoder<<<NB, NT, 0, stream>>>(enc, W1w, W1b, W2w, W2b,
                                             Wih, Whh, bih, bhh, (float*)d_out);
}